// Round 8
// baseline (1007.575 us; speedup 1.0000x reference)
//
#include <hip/hip_runtime.h>

// Decoder: 2-layer graph-conv LSTM, N=4096, B=32, C=16, H=64, K=3.
// bf16 MFMA supp GEMMs: 256x256 tile, BK=32, 64 KiB LDS + <=128 VGPR ->
// 2 blocks/CU (cross-block MFMA/stall overlap, m114), 4-phase counted-vmcnt
// pipeline (HW-verified in R5), rectangle-preserving XCD decode (R7).
// Fused bf16-MFMA gates + fp32 LSTM cell.

#define NN 4096
#define BB 32
#define HH 64

typedef __attribute__((ext_vector_type(8))) short short8;
typedef __attribute__((ext_vector_type(4))) float f32x4;

// memory-clobbered asm: LDS/VMEM ops cannot cross (correctness); register-only
// ops (MFMA, VALU) may (performance).
#define BARRIER asm volatile("s_barrier" ::: "memory")
#define VMCNT(n) asm volatile("s_waitcnt vmcnt(" #n ")" ::: "memory")

__device__ __forceinline__ unsigned short f2bf(float f) {
  unsigned int u = __float_as_uint(f);
  u += 0x7fffu + ((u >> 16) & 1u);
  return (unsigned short)(u >> 16);
}

// ---------------- G fp32 -> bf16 (vectorized) ----------------
__global__ __launch_bounds__(256) void cvt_kernel(const float* __restrict__ in,
                                                  unsigned short* __restrict__ out,
                                                  long n4) {
  long i = (long)blockIdx.x * 256 + threadIdx.x;
  if (i >= n4) return;
  float4 v = ((const float4*)in)[i];
  ushort4 o;
  o.x = f2bf(v.x); o.y = f2bf(v.y); o.z = f2bf(v.z); o.w = f2bf(v.w);
  ((ushort4*)out)[i] = o;
}

// ---------------- pack comb0^T : [2560][4096] bf16 ----------------
__global__ __launch_bounds__(256) void pack_comb0(const float* __restrict__ x,
                                                  const float* __restrict__ h,
                                                  unsigned short* __restrict__ cT) {
  __shared__ float tile[80][65];
  const int m0 = blockIdx.x * 64;
  const int b = blockIdx.y;
  const int t = threadIdx.x;
  for (int i = t; i < 64 * 16; i += 256) {
    int m = i >> 4, p = i & 15;
    tile[p][m] = x[((long)b * NN + m0 + m) * 16 + p];
  }
  for (int i = t; i < 64 * 64; i += 256) {
    int m = i >> 6, p = i & 63;
    tile[16 + p][m] = h[((long)b * NN + m0 + m) * 64 + p];
  }
  __syncthreads();
  for (int i = t; i < 80 * 64; i += 256) {
    int p = i >> 6, m = i & 63;
    cT[((long)(b * 80 + p)) * NN + m0 + m] = f2bf(tile[p][m]);
  }
}

// ---------------- pack h1 into comb1^T cols [b*128+64 ..] ----------------
__global__ __launch_bounds__(256) void pack_h1(const float* __restrict__ h,
                                               unsigned short* __restrict__ cT) {
  __shared__ float tile[64][65];
  const int m0 = blockIdx.x * 64;
  const int b = blockIdx.y;
  const int t = threadIdx.x;
  for (int i = t; i < 64 * 64; i += 256) {
    int m = i >> 6, p = i & 63;
    tile[p][m] = h[((long)b * NN + m0 + m) * 64 + p];
  }
  __syncthreads();
  for (int i = t; i < 64 * 64; i += 256) {
    int p = i >> 6, m = i & 63;
    cT[((long)(b * 128 + 64 + p)) * NN + m0 + m] = f2bf(tile[p][m]);
  }
}

// ---------------- W [KP][256] fp32 -> Wt [256][SP] bf16 (zero-pad) --------
__global__ __launch_bounds__(256) void prep_wt(const float* __restrict__ W,
                                               unsigned short* __restrict__ Wt,
                                               int KP, int SP) {
  int c = blockIdx.x;
  for (int k = threadIdx.x; k < SP; k += blockDim.x)
    Wt[(long)c * SP + k] = (k < KP) ? f2bf(W[(long)k * 256 + c]) : (unsigned short)0;
}

// ---------------- supp GEMM: 256x256 tile, BK=32, 8 waves, 4-phase ----------
// out[b,n,k,p] = sum_m G[k][n][m] * combT[b*P+p][m]
// LDS: 2 dbuf x (A 16KB + B 16KB) = 64 KiB -> 2 blocks/CU (with VGPR<=128).
// LDS layout: row-pairs in 128B lines; logical slot s0=(row&1)*4+kslot stored
// at s0 ^ (line&7). Stage: linear LDS dest + inverse-swizzled global source.
// 128 K-tiles of 32; ledger: outstanding at each VMCNT(2) = newest B-tile.
// Block decode: xcd = bid&7 (HW round-robin), kh-outer rectangle per R7.
template <int P, int SP, int RPK>
__global__ __launch_bounds__(512, 2) void gemm_supp32(const unsigned short* __restrict__ Gb,
                                                      const unsigned short* __restrict__ BT,
                                                      unsigned short* __restrict__ supp) {
  __shared__ short lds[2][2][256 * 32];  // 64 KiB
  const int t = threadIdx.x;
  const int w = t >> 6;
  const int lane = t & 63;
  const int lr = lane & 15;
  const int q = lane >> 4;
  const int wm = w >> 2;   // 0..1 : row half (128 rows)
  const int wn = w & 3;    // 0..3 : col band (64 cols)

  const int bid = blockIdx.x;
  const int xcd = bid & 7;
  const int rank = bid >> 3;
  const int kh = rank / RPK;
  const int jr = rank - kh * RPK;
  const int bm = xcd * 2 + (jr & 1);
  const int bc = jr >> 1;

  const short* Ag = (const short*)Gb + (long)kh * NN * NN + (long)bm * 256 * NN;
  const short* Bg = (const short*)BT + (long)bc * 256 * NN;

  // stage one 256x32 operand tile: 2 x global_load_lds(16B) per thread.
  auto stage = [&](int mat, int buf, int kt) {
    const short* base = (mat ? Bg : Ag) + kt * 32;
#pragma unroll
    for (int j = 0; j < 2; ++j) {
      int L = j * 512 + t;         // 16B-unit index 0..1023 (= LDS dest unit)
      int line = L >> 3;           // row-pair 0..127
      int sl = L & 7;              // stored slot
      int s0 = sl ^ (line & 7);    // logical slot
      int r = line * 2 + (s0 >> 2);
      int s = s0 & 3;              // k-slot (8 bf16)
      short* dst = &lds[buf][mat][(j * 512 + w * 64) * 8];  // wave-uniform base
      __builtin_amdgcn_global_load_lds(
          (const __attribute__((address_space(1))) void*)(base + (long)r * NN + s * 8),
          (__attribute__((address_space(3))) void*)dst, 16, 0, 0);
    }
  };

  auto ldfrag = [&](const short* m, int row) -> short8 {
    int line = row >> 1;
    int sl = (((row & 1) << 2) + q) ^ (line & 7);
    return *(const short8*)(m + line * 64 + sl * 8);
  };

  f32x4 acc[8][4] = {};
  short8 a4[4], bfr[4];

  auto dsB = [&](int buf) {
#pragma unroll
    for (int ni = 0; ni < 4; ++ni)
      bfr[ni] = ldfrag(&lds[buf][1][0], wn * 64 + ni * 16 + lr);
  };
  auto dsA = [&](int buf, int u) {
#pragma unroll
    for (int mi2 = 0; mi2 < 4; ++mi2)
      a4[mi2] = ldfrag(&lds[buf][0][0], wm * 128 + (u * 4 + mi2) * 16 + lr);
  };
  auto mmac = [&](int u) {
    __builtin_amdgcn_s_setprio(1);
#pragma unroll
    for (int mi2 = 0; mi2 < 4; ++mi2)
#pragma unroll
      for (int ni = 0; ni < 4; ++ni)
        acc[u * 4 + mi2][ni] =
            __builtin_amdgcn_mfma_f32_16x16x32_bf16(a4[mi2], bfr[ni], acc[u * 4 + mi2][ni], 0, 0, 0);
    __builtin_amdgcn_s_setprio(0);
  };

  // prologue: B0,A0 -> buf0; B1 -> buf1. vmcnt(2): B0,A0 landed; B1 in flight.
  stage(1, 0, 0);
  stage(0, 0, 0);
  stage(1, 1, 1);
  VMCNT(2);
  BARRIER;

  const int NT = NN / 32;  // 128 K-tiles
  for (int g = 0; g < NT; g += 2) {
    // P1: read tile g (buf0) u0; stage A(g+1)->buf1
    dsB(0); dsA(0, 0);
    stage(0, 1, g + 1);
    BARRIER; mmac(0); BARRIER;
    // P2: read tile g u1; stage B(g+2)->buf0; vmcnt leaves only B(g+2)
    dsA(0, 1);
    if (g + 2 < NT) stage(1, 0, g + 2);
    BARRIER; mmac(1);
    if (g + 2 < NT) { VMCNT(2); } else { VMCNT(0); }
    BARRIER;
    // P3: read tile g+1 (buf1) u0; stage A(g+2)->buf0
    dsB(1); dsA(1, 0);
    if (g + 2 < NT) stage(0, 0, g + 2);
    BARRIER; mmac(0); BARRIER;
    // P4: read tile g+1 u1; stage B(g+3)->buf1; vmcnt leaves only B(g+3)
    dsA(1, 1);
    if (g + 3 < NT) stage(1, 1, g + 3);
    BARRIER; mmac(1);
    VMCNT(2);
    BARRIER;
  }

  // Epilogue: D col=lane&15, row=(lane>>4)*4+i (verified layout); plain stores.
#pragma unroll
  for (int mi = 0; mi < 8; ++mi) {
#pragma unroll
    for (int ni = 0; ni < 4; ++ni) {
      int ccol = bc * 256 + wn * 64 + ni * 16 + lr;
      int b = ccol / P;
      int p = ccol - b * P;
#pragma unroll
      for (int i = 0; i < 4; ++i) {
        int n = bm * 256 + wm * 128 + mi * 16 + q * 4 + i;
        supp[((long)(b * NN + n)) * SP + kh * P + p] = f2bf(acc[mi][ni][i]);
      }
    }
  }
}

// ---------------- gates GEMM + LSTM cell, fused (32 tokens/wave) ----------
template <int SP, bool WBF, bool WH2>
__global__ __launch_bounds__(256) void gates_cell(const unsigned short* __restrict__ supp,
                                                  const unsigned short* __restrict__ Wt,
                                                  const float* __restrict__ bias,
                                                  const float* __restrict__ c_pre,
                                                  float* __restrict__ h_out,
                                                  float* __restrict__ c_out,
                                                  float* __restrict__ h_out2,
                                                  unsigned short* __restrict__ h_bf) {
  const int t = threadIdx.x;
  const int w = t >> 6;
  const int lane = t & 63;
  const int lr = lane & 15;
  const int q = lane >> 4;
  const long tok0 = (long)blockIdx.x * 128 + w * 32;
  f32x4 acc[2][16] = {};

  const short* sp0 = (const short*)supp + (tok0 + lr) * SP + q * 8;
  const short* sp1 = sp0 + 16 * SP;
  const short* wt = (const short*)Wt + (long)lr * SP + q * 8;
  for (int kk = 0; kk < SP / 32; ++kk) {
    short8 a0 = *(const short8*)(sp0 + kk * 32);
    short8 a1 = *(const short8*)(sp1 + kk * 32);
#pragma unroll
    for (int nf = 0; nf < 16; ++nf) {
      short8 b = *(const short8*)(wt + (long)nf * 16 * SP + kk * 32);
      acc[0][nf] = __builtin_amdgcn_mfma_f32_16x16x32_bf16(a0, b, acc[0][nf], 0, 0, 0);
      acc[1][nf] = __builtin_amdgcn_mfma_f32_16x16x32_bf16(a1, b, acc[1][nf], 0, 0, 0);
    }
  }
#pragma unroll
  for (int gi = 0; gi < 2; ++gi) {
#pragma unroll
    for (int i = 0; i < 4; ++i) {
      long tok = tok0 + gi * 16 + q * 4 + i;
      int bidx = (int)(tok >> 12);
      int n = (int)(tok & (NN - 1));
#pragma unroll
      for (int j = 0; j < 4; ++j) {
        int h = lr + 16 * j;
        float gi_ = acc[gi][j][i] + bias[h];
        float gf_ = acc[gi][j + 4][i] + bias[h + 64];
        float go_ = acc[gi][j + 8][i] + bias[h + 128];
        float gg_ = acc[gi][j + 12][i] + bias[h + 192];
        float cp = c_pre[tok * 64 + h];
        float ig = 1.f / (1.f + __expf(-gi_));
        float fg = 1.f / (1.f + __expf(-gf_));
        float og = 1.f / (1.f + __expf(-go_));
        float ct = fg * cp + ig * tanhf(gg_);
        float ht = og * tanhf(ct);
        c_out[tok * 64 + h] = ct;
        h_out[tok * 64 + h] = ht;
        if (WH2) h_out2[tok * 64 + h] = ht;
        if (WBF) h_bf[((long)(bidx * 128 + h)) * NN + n] = f2bf(ht);
      }
    }
  }
}

extern "C" void kernel_launch(void* const* d_in, const int* in_sizes, int n_in,
                              void* d_out, int out_size, void* d_ws, size_t ws_size,
                              hipStream_t stream) {
  const float* G  = (const float*)d_in[0];
  const float* x_t = (const float*)d_in[1];
  const float* h0 = (const float*)d_in[2];
  const float* h1 = (const float*)d_in[3];
  const float* c0 = (const float*)d_in[4];
  const float* c1 = (const float*)d_in[5];
  const float* W0 = (const float*)d_in[6];
  const float* b0 = (const float*)d_in[7];
  const float* W1 = (const float*)d_in[8];
  const float* b1 = (const float*)d_in[9];
  float* out = (float*)d_out;
  const long M = 8388608L;  // B*N*H

  char* ws = (char*)d_ws;
  unsigned short* Gb    = (unsigned short*)(ws);               // 100,663,296 B
  unsigned short* c0T   = (unsigned short*)(ws + 100663296L);  //  20,971,520 B
  unsigned short* c1T   = (unsigned short*)(ws + 121634816L);  //  33,554,432 B
  unsigned short* supp1 = (unsigned short*)(ws + 155189248L);  // 100,663,296 B
  unsigned short* supp0 = supp1;  // aliased (dead before gemm1 writes)
  unsigned short* Wt0   = (unsigned short*)(ws + 255852544L);
  unsigned short* Wt1   = (unsigned short*)(ws + 255983616L);

  // zero layer-0 supp pad cols (KP=240 padded to SP=256)
  hipMemsetAsync(supp0, 0, (size_t)131072 * 256 * 2, stream);

  cvt_kernel<<<49152, 256, 0, stream>>>(G, Gb, 12582912L);
  pack_comb0<<<dim3(64, 32), 256, 0, stream>>>(x_t, h0, c0T);
  pack_h1<<<dim3(64, 32), 256, 0, stream>>>(h1, c1T);
  prep_wt<<<dim3(256), 256, 0, stream>>>(W0, Wt0, 240, 256);
  prep_wt<<<dim3(256), 256, 0, stream>>>(W1, Wt1, 384, 384);

  // layer 0: 16 bm x 10 bc x 3 kh = 480 blocks; RPK = 20 ranks per kh
  gemm_supp32<80, 256, 20><<<480, 512, 0, stream>>>(Gb, c0T, supp0);
  gates_cell<256, true, false><<<1024, 256, 0, stream>>>(
      supp0, Wt0, b0, c0, out + M, out + 3 * M, nullptr, c1T);
  // layer 1: 16 bm x 16 bc x 3 kh = 768 blocks; RPK = 32
  gemm_supp32<128, 384, 32><<<768, 512, 0, stream>>>(Gb, c1T, supp1);
  gates_cell<384, false, true><<<1024, 256, 0, stream>>>(
      supp1, Wt1, b1, c1, out, out + 4 * M, out + 2 * M, nullptr);
}

// Round 9
// 951.056 us; speedup vs baseline: 1.0594x; 1.0594x over previous
//
#include <hip/hip_runtime.h>

// Decoder: 2-layer graph-conv LSTM, N=4096, B=32, C=16, H=64, K=3.
// supp GEMMs: 256x256 tile, BK=64, 8 waves, m201-style 8-phase schedule:
// {ds-reads + 1 half-tile stage} pre-barrier, {16 MFMA} post-barrier,
// counted VMCNT(2) at P4/P8 only. 1 block/CU is structural (128 acc regs).
// Rectangle-preserving XCD decode. Fused bf16-MFMA gates + fp32 LSTM cell.

#define NN 4096
#define BB 32
#define HH 64

typedef __attribute__((ext_vector_type(8))) short short8;
typedef __attribute__((ext_vector_type(4))) float f32x4;

#define BARRIER asm volatile("s_barrier" ::: "memory")
#define VMCNT(n) asm volatile("s_waitcnt vmcnt(" #n ")" ::: "memory")

__device__ __forceinline__ unsigned short f2bf(float f) {
  unsigned int u = __float_as_uint(f);
  u += 0x7fffu + ((u >> 16) & 1u);
  return (unsigned short)(u >> 16);
}

// ---------------- G fp32 -> bf16 (vectorized) ----------------
__global__ __launch_bounds__(256) void cvt_kernel(const float* __restrict__ in,
                                                  unsigned short* __restrict__ out,
                                                  long n4) {
  long i = (long)blockIdx.x * 256 + threadIdx.x;
  if (i >= n4) return;
  float4 v = ((const float4*)in)[i];
  ushort4 o;
  o.x = f2bf(v.x); o.y = f2bf(v.y); o.z = f2bf(v.z); o.w = f2bf(v.w);
  ((ushort4*)out)[i] = o;
}

// ---------------- pack comb0^T : [2560][4096] bf16 ----------------
__global__ __launch_bounds__(256) void pack_comb0(const float* __restrict__ x,
                                                  const float* __restrict__ h,
                                                  unsigned short* __restrict__ cT) {
  __shared__ float tile[80][65];
  const int m0 = blockIdx.x * 64;
  const int b = blockIdx.y;
  const int t = threadIdx.x;
  for (int i = t; i < 64 * 16; i += 256) {
    int m = i >> 4, p = i & 15;
    tile[p][m] = x[((long)b * NN + m0 + m) * 16 + p];
  }
  for (int i = t; i < 64 * 64; i += 256) {
    int m = i >> 6, p = i & 63;
    tile[16 + p][m] = h[((long)b * NN + m0 + m) * 64 + p];
  }
  __syncthreads();
  for (int i = t; i < 80 * 64; i += 256) {
    int p = i >> 6, m = i & 63;
    cT[((long)(b * 80 + p)) * NN + m0 + m] = f2bf(tile[p][m]);
  }
}

// ---------------- pack h1 into comb1^T cols [b*128+64 ..] ----------------
__global__ __launch_bounds__(256) void pack_h1(const float* __restrict__ h,
                                               unsigned short* __restrict__ cT) {
  __shared__ float tile[64][65];
  const int m0 = blockIdx.x * 64;
  const int b = blockIdx.y;
  const int t = threadIdx.x;
  for (int i = t; i < 64 * 64; i += 256) {
    int m = i >> 6, p = i & 63;
    tile[p][m] = h[((long)b * NN + m0 + m) * 64 + p];
  }
  __syncthreads();
  for (int i = t; i < 64 * 64; i += 256) {
    int p = i >> 6, m = i & 63;
    cT[((long)(b * 128 + 64 + p)) * NN + m0 + m] = f2bf(tile[p][m]);
  }
}

// ---------------- W [KP][256] fp32 -> Wt [256][SP] bf16 (zero-pad) --------
__global__ __launch_bounds__(256) void prep_wt(const float* __restrict__ W,
                                               unsigned short* __restrict__ Wt,
                                               int KP, int SP) {
  int c = blockIdx.x;
  for (int k = threadIdx.x; k < SP; k += blockDim.x)
    Wt[(long)c * SP + k] = (k < KP) ? f2bf(W[(long)k * 256 + c]) : (unsigned short)0;
}

// ---------------- supp GEMM: 256x256, BK=64, 8 waves, m201 8-phase ----------
// out[b,n,k,p] = sum_m G[k][n][m] * combT[b*P+p][m]
// LDS 128 KiB = 2 dbuf x (A 32K + B 32K). Per phase: {reads(4-8 b128) +
// 1 half-tile stage (2 gload_lds)} pre-barrier; {16 MFMA} post-barrier.
// Stage slots (group g, t=2g): P1 Atop(t+1), P2 Abot(t+1), P3 Bbot(t+1),
// P4 Btop(t+2)+VMCNT(2), P5 Atop(t+2), P6 Abot(t+2), P7 Bbot(t+2),
// P8 Btop(t+3)+VMCNT(2). Ledger verified: at each VMCNT(2) only the newest
// half is in flight; every read's halves landed; overwrites barrier-closed.
template <int P, int SP, int RPK>
__global__ __launch_bounds__(512, 2) void gemm_supp8(const unsigned short* __restrict__ Gb,
                                                     const unsigned short* __restrict__ BT,
                                                     unsigned short* __restrict__ supp) {
  __shared__ short lds[2][2][256 * 64];  // 128 KiB
  const int t = threadIdx.x;
  const int w = t >> 6;
  const int lane = t & 63;
  const int lr = lane & 15;
  const int q = lane >> 4;
  const int wm = w >> 2;   // 0..1 : row half (128 rows)
  const int wn = w & 3;    // 0..3 : col band (64 cols)

  const int bid = blockIdx.x;
  const int xcd = bid & 7;
  const int rank = bid >> 3;
  const int kh = rank / RPK;
  const int jr = rank - kh * RPK;
  const int bm = xcd * 2 + (jr & 1);
  const int bc = jr >> 1;

  const short* Ag = (const short*)Gb + (long)kh * NN * NN + (long)bm * 256 * NN;
  const short* Bg = (const short*)BT + (long)bc * 256 * NN;

  // stage one row-half (128 rows x 64 k) of operand mat, K-tile kt, into buf.
  // linear LDS dest + XOR-pre-swizzled global source (rule #21).
  auto stage = [&](int mat, int buf, int kt, int half) {
    const short* base = (mat ? Bg : Ag) + kt * 64;
#pragma unroll
    for (int j = 0; j < 2; ++j) {
      int L = j * 512 + t;          // unit 0..1023 within half
      int rl = L >> 3;              // local row 0..127
      int sl = L & 7;               // stored 16B slot
      int r = half * 128 + rl;      // global row
      int s0 = sl ^ (r & 7);        // logical (source) slot
      short* dst = &lds[buf][mat][(half * 1024 + j * 512 + w * 64) * 8];
      __builtin_amdgcn_global_load_lds(
          (const __attribute__((address_space(1))) void*)(base + (long)r * NN + s0 * 8),
          (__attribute__((address_space(3))) void*)dst, 16, 0, 0);
    }
  };

  f32x4 acc[8][4] = {};
  short8 a4[4], bfr[4];

  auto rdA = [&](int buf, int u, int ks) {
#pragma unroll
    for (int mi = 0; mi < 4; ++mi) {
      int row = wm * 128 + (u * 4 + mi) * 16 + lr;
      int slot = (ks * 4 + q) ^ (row & 7);
      a4[mi] = *(const short8*)&lds[buf][0][row * 64 + slot * 8];
    }
  };
  auto rdB = [&](int buf, int ks) {
#pragma unroll
    for (int ni = 0; ni < 4; ++ni) {
      int row = wn * 64 + ni * 16 + lr;
      int slot = (ks * 4 + q) ^ (row & 7);
      bfr[ni] = *(const short8*)&lds[buf][1][row * 64 + slot * 8];
    }
  };
  auto mmac = [&](int u) {
    __builtin_amdgcn_s_setprio(1);
#pragma unroll
    for (int mi = 0; mi < 4; ++mi)
#pragma unroll
      for (int ni = 0; ni < 4; ++ni)
        acc[u * 4 + mi][ni] =
            __builtin_amdgcn_mfma_f32_16x16x32_bf16(a4[mi], bfr[ni], acc[u * 4 + mi][ni], 0, 0, 0);
    __builtin_amdgcn_s_setprio(0);
  };

  // prologue: tile0 (4 halves) -> buf0; Btop(1) -> buf1 (= steady "prev P8").
  stage(0, 0, 0, 0); stage(0, 0, 0, 1);
  stage(1, 0, 0, 0); stage(1, 0, 0, 1);
  stage(1, 1, 1, 0);
  VMCNT(2);
  BARRIER;

  for (int g = 0; g < 32; ++g) {
    const int tk = 2 * g;
    // P1: tile tk (buf0) u0,k0
    rdB(0, 0); rdA(0, 0, 0);
    stage(0, 1, tk + 1, 0);                 // Atop(t+1)
    BARRIER; mmac(0); BARRIER;
    // P2: u1,k0 (reuse bfr)
    rdA(0, 1, 0);
    stage(0, 1, tk + 1, 1);                 // Abot(t+1)
    BARRIER; mmac(1); BARRIER;
    // P3: u0,k1
    rdB(0, 1); rdA(0, 0, 1);
    stage(1, 1, tk + 1, 1);                 // Bbot(t+1)
    BARRIER; mmac(0); BARRIER;
    // P4: u1,k1
    rdA(0, 1, 1);
    if (tk + 2 < 64) { stage(1, 0, tk + 2, 0); VMCNT(2); }  // Btop(t+2)
    else             { VMCNT(0); }
    BARRIER; mmac(1); BARRIER;
    // P5: tile tk+1 (buf1) u0,k0
    rdB(1, 0); rdA(1, 0, 0);
    if (tk + 2 < 64) stage(0, 0, tk + 2, 0);  // Atop(t+2)
    BARRIER; mmac(0); BARRIER;
    // P6: u1,k0
    rdA(1, 1, 0);
    if (tk + 2 < 64) stage(0, 0, tk + 2, 1);  // Abot(t+2)
    BARRIER; mmac(1); BARRIER;
    // P7: u0,k1
    rdB(1, 1); rdA(1, 0, 1);
    if (tk + 2 < 64) stage(1, 0, tk + 2, 1);  // Bbot(t+2)
    BARRIER; mmac(0); BARRIER;
    // P8: u1,k1
    rdA(1, 1, 1);
    if (tk + 3 < 64) { stage(1, 1, tk + 3, 0); VMCNT(2); }  // Btop(t+3)
    else             { VMCNT(0); }
    BARRIER; mmac(1); BARRIER;
  }

  // Epilogue: D col=lane&15, row=(lane>>4)*4+i (verified); plain stores.
#pragma unroll
  for (int mi = 0; mi < 8; ++mi) {
#pragma unroll
    for (int ni = 0; ni < 4; ++ni) {
      int ccol = bc * 256 + wn * 64 + ni * 16 + lr;
      int b = ccol / P;
      int p = ccol - b * P;
#pragma unroll
      for (int i = 0; i < 4; ++i) {
        int n = bm * 256 + wm * 128 + mi * 16 + q * 4 + i;
        supp[((long)(b * NN + n)) * SP + kh * P + p] = f2bf(acc[mi][ni][i]);
      }
    }
  }
}

// ---------------- gates GEMM + LSTM cell, fused (32 tokens/wave) ----------
template <int SP, bool WBF, bool WH2>
__global__ __launch_bounds__(256) void gates_cell(const unsigned short* __restrict__ supp,
                                                  const unsigned short* __restrict__ Wt,
                                                  const float* __restrict__ bias,
                                                  const float* __restrict__ c_pre,
                                                  float* __restrict__ h_out,
                                                  float* __restrict__ c_out,
                                                  float* __restrict__ h_out2,
                                                  unsigned short* __restrict__ h_bf) {
  const int t = threadIdx.x;
  const int w = t >> 6;
  const int lane = t & 63;
  const int lr = lane & 15;
  const int q = lane >> 4;
  const long tok0 = (long)blockIdx.x * 128 + w * 32;
  f32x4 acc[2][16] = {};

  const short* sp0 = (const short*)supp + (tok0 + lr) * SP + q * 8;
  const short* sp1 = sp0 + 16 * SP;
  const short* wt = (const short*)Wt + (long)lr * SP + q * 8;
  for (int kk = 0; kk < SP / 32; ++kk) {
    short8 a0 = *(const short8*)(sp0 + kk * 32);
    short8 a1 = *(const short8*)(sp1 + kk * 32);
#pragma unroll
    for (int nf = 0; nf < 16; ++nf) {
      short8 b = *(const short8*)(wt + (long)nf * 16 * SP + kk * 32);
      acc[0][nf] = __builtin_amdgcn_mfma_f32_16x16x32_bf16(a0, b, acc[0][nf], 0, 0, 0);
      acc[1][nf] = __builtin_amdgcn_mfma_f32_16x16x32_bf16(a1, b, acc[1][nf], 0, 0, 0);
    }
  }
#pragma unroll
  for (int gi = 0; gi < 2; ++gi) {
#pragma unroll
    for (int i = 0; i < 4; ++i) {
      long tok = tok0 + gi * 16 + q * 4 + i;
      int bidx = (int)(tok >> 12);
      int n = (int)(tok & (NN - 1));
#pragma unroll
      for (int j = 0; j < 4; ++j) {
        int h = lr + 16 * j;
        float gi_ = acc[gi][j][i] + bias[h];
        float gf_ = acc[gi][j + 4][i] + bias[h + 64];
        float go_ = acc[gi][j + 8][i] + bias[h + 128];
        float gg_ = acc[gi][j + 12][i] + bias[h + 192];
        float cp = c_pre[tok * 64 + h];
        float ig = 1.f / (1.f + __expf(-gi_));
        float fg = 1.f / (1.f + __expf(-gf_));
        float og = 1.f / (1.f + __expf(-go_));
        float ct = fg * cp + ig * tanhf(gg_);
        float ht = og * tanhf(ct);
        c_out[tok * 64 + h] = ct;
        h_out[tok * 64 + h] = ht;
        if (WH2) h_out2[tok * 64 + h] = ht;
        if (WBF) h_bf[((long)(bidx * 128 + h)) * NN + n] = f2bf(ht);
      }
    }
  }
}

extern "C" void kernel_launch(void* const* d_in, const int* in_sizes, int n_in,
                              void* d_out, int out_size, void* d_ws, size_t ws_size,
                              hipStream_t stream) {
  const float* G  = (const float*)d_in[0];
  const float* x_t = (const float*)d_in[1];
  const float* h0 = (const float*)d_in[2];
  const float* h1 = (const float*)d_in[3];
  const float* c0 = (const float*)d_in[4];
  const float* c1 = (const float*)d_in[5];
  const float* W0 = (const float*)d_in[6];
  const float* b0 = (const float*)d_in[7];
  const float* W1 = (const float*)d_in[8];
  const float* b1 = (const float*)d_in[9];
  float* out = (float*)d_out;
  const long M = 8388608L;  // B*N*H

  char* ws = (char*)d_ws;
  unsigned short* Gb    = (unsigned short*)(ws);               // 100,663,296 B
  unsigned short* c0T   = (unsigned short*)(ws + 100663296L);  //  20,971,520 B
  unsigned short* c1T   = (unsigned short*)(ws + 121634816L);  //  33,554,432 B
  unsigned short* supp1 = (unsigned short*)(ws + 155189248L);  // 100,663,296 B
  unsigned short* supp0 = supp1;  // aliased (dead before gemm1 writes)
  unsigned short* Wt0   = (unsigned short*)(ws + 255852544L);
  unsigned short* Wt1   = (unsigned short*)(ws + 255983616L);

  // zero layer-0 supp pad cols (KP=240 padded to SP=256)
  hipMemsetAsync(supp0, 0, (size_t)131072 * 256 * 2, stream);

  cvt_kernel<<<49152, 256, 0, stream>>>(G, Gb, 12582912L);
  pack_comb0<<<dim3(64, 32), 256, 0, stream>>>(x_t, h0, c0T);
  pack_h1<<<dim3(64, 32), 256, 0, stream>>>(h1, c1T);
  prep_wt<<<dim3(256), 256, 0, stream>>>(W0, Wt0, 240, 256);
  prep_wt<<<dim3(256), 256, 0, stream>>>(W1, Wt1, 384, 384);

  // layer 0: 16 bm x 10 bc x 3 kh = 480 blocks; RPK = 20 ranks per kh
  gemm_supp8<80, 256, 20><<<480, 512, 0, stream>>>(Gb, c0T, supp0);
  gates_cell<256, true, false><<<1024, 256, 0, stream>>>(
      supp0, Wt0, b0, c0, out + M, out + 3 * M, nullptr, c1T);
  // layer 1: 16 bm x 16 bc x 3 kh = 768 blocks; RPK = 32
  gemm_supp8<128, 384, 32><<<768, 512, 0, stream>>>(Gb, c1T, supp1);
  gates_cell<384, false, true><<<1024, 256, 0, stream>>>(
      supp1, Wt1, b1, c1, out, out + 4 * M, out + 2 * M, nullptr);
}